// Round 1
// baseline (768.157 us; speedup 1.0000x reference)
//
#include <hip/hip_runtime.h>

#define K_DIM 4096
#define O_DIM 11008
#define QBLK  256
#define BPR   (K_DIM / QBLK)   // 16

typedef _Float16 f16;
typedef _Float16 f16x8 __attribute__((ext_vector_type(8)));
typedef float    f32x4 __attribute__((ext_vector_type(4)));

// ---------------- kernel 1: x fp32 -> f16 ----------------
__global__ __launch_bounds__(256) void cvt_x_kernel(const float* __restrict__ x,
                                                    f16* __restrict__ xh) {
    size_t i = ((size_t)blockIdx.x * 256 + threadIdx.x) * 8;
    float4 a = *(const float4*)(x + i);
    float4 b = *(const float4*)(x + i + 4);
    f16x8 h;
    h[0] = (f16)a.x; h[1] = (f16)a.y; h[2] = (f16)a.z; h[3] = (f16)a.w;
    h[4] = (f16)b.x; h[5] = (f16)b.y; h[6] = (f16)b.z; h[7] = (f16)b.w;
    *(f16x8*)(xh + i) = h;
}

// ---------------- kernel 2: dequant W -> f16 ----------------
// W[o,i] = ((q-128)/127)*s + b = q*(s/127) + (b - 128*s/127)
__global__ __launch_bounds__(256) void dequant_w_kernel(const int* __restrict__ qidx,
                                                        const float* __restrict__ scales,
                                                        const float* __restrict__ babs,
                                                        f16* __restrict__ wh) {
    size_t e = ((size_t)blockIdx.x * 256 + threadIdx.x) * 8;
    int4 q0 = *(const int4*)(qidx + e);
    int4 q1 = *(const int4*)(qidx + e + 4);
    int sb = (int)(e >> 8);                 // e/256: same block for all 8 elems
    float s2 = scales[sb] * (1.0f / 127.0f);
    float b2 = fmaf(-128.0f, s2, babs[sb]);
    f16x8 h;
    h[0] = (f16)fmaf((float)q0.x, s2, b2);
    h[1] = (f16)fmaf((float)q0.y, s2, b2);
    h[2] = (f16)fmaf((float)q0.z, s2, b2);
    h[3] = (f16)fmaf((float)q0.w, s2, b2);
    h[4] = (f16)fmaf((float)q1.x, s2, b2);
    h[5] = (f16)fmaf((float)q1.y, s2, b2);
    h[6] = (f16)fmaf((float)q1.z, s2, b2);
    h[7] = (f16)fmaf((float)q1.w, s2, b2);
    *(f16x8*)(wh + e) = h;
}

// ---------------- kernel 3: 128x128 f16 MFMA GEMM (B^T layout) ----------------
// A: [nrows, K] f16 row-major (x).  B: [O, K] f16 row-major (W).
// out[n,o] = sum_k A[n,k]*B[o,k] + bias[o], fp32.
#define BM 128
#define BN 128
#define BK 64
#define NBN (O_DIM / BN)   // 86

__global__ __launch_bounds__(256, 3) void gemm_f16_kernel(const f16* __restrict__ A,
                                                          const f16* __restrict__ B,
                                                          const float* __restrict__ bias,
                                                          float* __restrict__ out) {
    __shared__ f16 As[BM * BK];   // [128][64] row-major, 16 KB
    __shared__ f16 Bs[BN * BK];   // [128][64] row-major, 16 KB

    // bijective XCD swizzle (gridDim.x % 8 == 0 guaranteed by launch)
    int bid = blockIdx.x;
    int chunk = gridDim.x >> 3;
    int swz = (bid & 7) * chunk + (bid >> 3);
    int bm = swz / NBN;
    int bn = swz - bm * NBN;

    const int tid  = threadIdx.x;
    const int lane = tid & 63;
    const int wid  = tid >> 6;
    const int wr   = wid >> 1;        // wave row in 2x2
    const int wc   = wid & 1;         // wave col in 2x2
    const int fr   = lane & 15;       // fragment row/col (M or N index)
    const int fq   = lane >> 4;       // K-quad

    const size_t arow0 = (size_t)bm * BM;
    const size_t brow0 = (size_t)bn * BN;
    const f16* ga = A + arow0 * K_DIM;
    const f16* gb = B + brow0 * K_DIM;

    f32x4 acc[4][4];
    #pragma unroll
    for (int m = 0; m < 4; ++m)
        #pragma unroll
        for (int n = 0; n < 4; ++n)
            acc[m][n] = (f32x4){0.f, 0.f, 0.f, 0.f};

    for (int kt = 0; kt < K_DIM / BK; ++kt) {
        const int k0 = kt * BK;
        // stage 16KB A + 16KB B: 4 chunks of (256 thr x 16B) each
        #pragma unroll
        for (int c = 0; c < 4; ++c) {
            int bo  = (c * 256 + tid) * 16;     // byte offset in tile
            int row = bo >> 7;                  // 128 B per row
            int col = (bo & 127) >> 1;          // f16 index within row
            __builtin_amdgcn_global_load_lds(
                (const __attribute__((address_space(1))) void*)(ga + (size_t)row * K_DIM + k0 + col),
                (__attribute__((address_space(3))) void*)(As + (bo >> 1)),
                16, 0, 0);
            __builtin_amdgcn_global_load_lds(
                (const __attribute__((address_space(1))) void*)(gb + (size_t)row * K_DIM + k0 + col),
                (__attribute__((address_space(3))) void*)(Bs + (bo >> 1)),
                16, 0, 0);
        }
        __syncthreads();   // compiler emits vmcnt(0) drain before barrier

        #pragma unroll
        for (int kk = 0; kk < 2; ++kk) {
            f16x8 af[4], bf[4];
            #pragma unroll
            for (int m = 0; m < 4; ++m)
                af[m] = *(const f16x8*)(As + (wr * 64 + m * 16 + fr) * BK + kk * 32 + fq * 8);
            #pragma unroll
            for (int n = 0; n < 4; ++n)
                bf[n] = *(const f16x8*)(Bs + (wc * 64 + n * 16 + fr) * BK + kk * 32 + fq * 8);
            #pragma unroll
            for (int m = 0; m < 4; ++m)
                #pragma unroll
                for (int n = 0; n < 4; ++n)
                    acc[m][n] = __builtin_amdgcn_mfma_f32_16x16x32_f16(af[m], bf[n], acc[m][n], 0, 0, 0);
        }
        __syncthreads();
    }

    // epilogue: C/D layout col=lane&15, row=(lane>>4)*4+r  (guide §3, m89-verified)
    #pragma unroll
    for (int m = 0; m < 4; ++m) {
        int grow = (int)arow0 + wr * 64 + m * 16 + fq * 4;
        #pragma unroll
        for (int n = 0; n < 4; ++n) {
            int gcol = (int)brow0 + wc * 64 + n * 16 + fr;
            float bv = bias[gcol];
            #pragma unroll
            for (int r = 0; r < 4; ++r)
                out[(size_t)(grow + r) * O_DIM + gcol] = acc[m][n][r] + bv;
        }
    }
}

// ---------------- fallback (only if ws too small): correctness-first ----------------
__global__ __launch_bounds__(256) void fallback_kernel(const float* __restrict__ x,
                                                       const int* __restrict__ qidx,
                                                       const float* __restrict__ scales,
                                                       const float* __restrict__ babs,
                                                       const float* __restrict__ bias,
                                                       float* __restrict__ out) {
    __shared__ float xs[K_DIM];
    int n = blockIdx.x;
    int o = blockIdx.y * 256 + threadIdx.x;
    for (int i = threadIdx.x; i < K_DIM; i += 256)
        xs[i] = x[(size_t)n * K_DIM + i];
    __syncthreads();
    const int* qr = qidx + (size_t)o * K_DIM;
    float sum = 0.f;
    for (int b = 0; b < BPR; ++b) {
        float s2 = scales[o * BPR + b] * (1.0f / 127.0f);
        float b2 = fmaf(-128.0f, s2, babs[o * BPR + b]);
        for (int k = 0; k < QBLK; ++k)
            sum = fmaf(xs[b * QBLK + k], fmaf((float)qr[b * QBLK + k], s2, b2), sum);
    }
    out[(size_t)n * O_DIM + o] = sum + bias[o];
}

extern "C" void kernel_launch(void* const* d_in, const int* in_sizes, int n_in,
                              void* d_out, int out_size, void* d_ws, size_t ws_size,
                              hipStream_t stream) {
    const float* x      = (const float*)d_in[0];
    const int*   qidx   = (const int*)d_in[1];
    const float* scales = (const float*)d_in[2];
    const float* babs   = (const float*)d_in[3];
    const float* bias   = (const float*)d_in[4];
    float* out = (float*)d_out;

    const int nrows = in_sizes[0] / K_DIM;   // 4096

    const size_t xh_bytes = (size_t)nrows * K_DIM * sizeof(f16);       // 33.5 MB
    const size_t wh_bytes = (size_t)O_DIM * K_DIM * sizeof(f16);       // 90.2 MB

    if (ws_size >= xh_bytes + wh_bytes) {
        f16* xh = (f16*)d_ws;
        f16* wh = (f16*)((char*)d_ws + xh_bytes);

        int cvt_blocks = (int)(((size_t)nrows * K_DIM) / 2048);        // 8192
        cvt_x_kernel<<<cvt_blocks, 256, 0, stream>>>(x, xh);

        int dq_blocks = (int)(((size_t)O_DIM * K_DIM) / 2048);         // 22016
        dequant_w_kernel<<<dq_blocks, 256, 0, stream>>>(qidx, scales, babs, wh);

        int nwg = (nrows / BM) * NBN;                                  // 32*86 = 2752, %8==0
        gemm_f16_kernel<<<nwg, 256, 0, stream>>>(xh, wh, bias, out);
    } else {
        dim3 grid(nrows, O_DIM / 256);
        fallback_kernel<<<grid, 256, 0, stream>>>(x, qidx, scales, babs, bias, out);
    }
}

// Round 2
// 727.244 us; speedup vs baseline: 1.0563x; 1.0563x over previous
//
#include <hip/hip_runtime.h>

#define K_DIM 4096
#define O_DIM 11008
#define QBLK  256
#define BPR   (K_DIM / QBLK)   // 16

typedef _Float16 f16;
typedef _Float16 f16x8 __attribute__((ext_vector_type(8)));
typedef float    f32x4 __attribute__((ext_vector_type(4)));

// ---------------- kernel 1: x fp32 -> f16 ----------------
__global__ __launch_bounds__(256) void cvt_x_kernel(const float* __restrict__ x,
                                                    f16* __restrict__ xh) {
    size_t i = ((size_t)blockIdx.x * 256 + threadIdx.x) * 8;
    float4 a = *(const float4*)(x + i);
    float4 b = *(const float4*)(x + i + 4);
    f16x8 h;
    h[0] = (f16)a.x; h[1] = (f16)a.y; h[2] = (f16)a.z; h[3] = (f16)a.w;
    h[4] = (f16)b.x; h[5] = (f16)b.y; h[6] = (f16)b.z; h[7] = (f16)b.w;
    *(f16x8*)(xh + i) = h;
}

// ---------------- kernel 2: dequant W -> f16 ----------------
__global__ __launch_bounds__(256) void dequant_w_kernel(const int* __restrict__ qidx,
                                                        const float* __restrict__ scales,
                                                        const float* __restrict__ babs,
                                                        f16* __restrict__ wh) {
    size_t e = ((size_t)blockIdx.x * 256 + threadIdx.x) * 8;
    int4 q0 = *(const int4*)(qidx + e);
    int4 q1 = *(const int4*)(qidx + e + 4);
    int sb = (int)(e >> 8);
    float s2 = scales[sb] * (1.0f / 127.0f);
    float b2 = fmaf(-128.0f, s2, babs[sb]);
    f16x8 h;
    h[0] = (f16)fmaf((float)q0.x, s2, b2);
    h[1] = (f16)fmaf((float)q0.y, s2, b2);
    h[2] = (f16)fmaf((float)q0.z, s2, b2);
    h[3] = (f16)fmaf((float)q0.w, s2, b2);
    h[4] = (f16)fmaf((float)q1.x, s2, b2);
    h[5] = (f16)fmaf((float)q1.y, s2, b2);
    h[6] = (f16)fmaf((float)q1.z, s2, b2);
    h[7] = (f16)fmaf((float)q1.w, s2, b2);
    *(f16x8*)(wh + e) = h;
}

// ---------------- kernel 3: 256x256 tile, BK=32, 4-deep ring, counted vmcnt ----------------
// A: [4096, K] f16 row-major (x_f16).  B: [O, K] f16 row-major (W_f16).
// out[n,o] = sum_k A[n,k]*B[o,k] + bias[o], fp32.
#define BM 256
#define BN 256
#define BK 32
#define NT (K_DIM / BK)        // 128 K-tiles
#define NBN (O_DIM / BN)       // 43
#define TILE_E (BM * BK)       // 8192 f16 per operand per buffer

__global__ __launch_bounds__(512, 2) void gemm256_f16_kernel(const f16* __restrict__ A,
                                                             const f16* __restrict__ B,
                                                             const float* __restrict__ bias,
                                                             float* __restrict__ out) {
    // 4 ring buffers x {A,B} x 8192 f16 = 128 KiB
    __shared__ f16 smem[4][2][TILE_E];

    // bijective XCD swizzle (688 blocks, 688 % 8 == 0)
    int bid = blockIdx.x;
    int chunk = gridDim.x >> 3;
    int swz = (bid & 7) * chunk + (bid >> 3);
    int bm = swz / NBN;
    int bn = swz - bm * NBN;

    const int tid  = threadIdx.x;
    const int lane = tid & 63;
    const int wid  = tid >> 6;          // 8 waves
    const int wr   = wid >> 2;          // 0..1  -> rows wr*128
    const int wc   = wid & 3;           // 0..3  -> cols wc*64
    const int fr   = lane & 15;
    const int fq   = lane >> 4;

    const f16* gA = A + (size_t)bm * BM * K_DIM;
    const f16* gB = B + (size_t)bn * BN * K_DIM;

    // ---- staging address precompute (source pre-swizzled, LDS dest linear) ----
    // LDS slot s at row r holds logical k-slot s ^ ((r>>1)&3)  (16B slots, 4 per 64B row)
    const int srow  = tid >> 2;                         // 0..127 (+128 for chunk 1)
    const int sslot = (tid & 3) ^ ((tid >> 3) & 3);     // = (tid&3) ^ ((srow>>1)&3)
    const size_t goff = (size_t)srow * K_DIM + sslot * 8;   // f16 elems
    const int loff = tid * 8;                           // f16 elems (linear dest)

    // ---- fragment read offsets (swizzled), within an 8192-elem region ----
    int aoffs[8], boffs[4];
    #pragma unroll
    for (int m = 0; m < 8; ++m) {
        int r = wr * 128 + m * 16 + fr;
        aoffs[m] = r * BK + ((fq ^ ((r >> 1) & 3)) << 3);
    }
    #pragma unroll
    for (int n = 0; n < 4; ++n) {
        int r = wc * 64 + n * 16 + fr;
        boffs[n] = r * BK + ((fq ^ ((r >> 1) & 3)) << 3);
    }

    f32x4 acc[8][4];
    #pragma unroll
    for (int m = 0; m < 8; ++m)
        #pragma unroll
        for (int n = 0; n < 4; ++n)
            acc[m][n] = (f32x4){0.f, 0.f, 0.f, 0.f};

#define STAGE(tt)                                                                        \
    do {                                                                                 \
        int _b = (tt) & 3;                                                               \
        size_t _k = (size_t)(tt) * BK;                                                   \
        __builtin_amdgcn_global_load_lds(                                                \
            (const __attribute__((address_space(1))) void*)(gA + _k + goff),             \
            (__attribute__((address_space(3))) void*)(&smem[_b][0][loff]), 16, 0, 0);    \
        __builtin_amdgcn_global_load_lds(                                                \
            (const __attribute__((address_space(1))) void*)(gA + _k + goff + (size_t)128 * K_DIM), \
            (__attribute__((address_space(3))) void*)(&smem[_b][0][loff + 4096]), 16, 0, 0); \
        __builtin_amdgcn_global_load_lds(                                                \
            (const __attribute__((address_space(1))) void*)(gB + _k + goff),             \
            (__attribute__((address_space(3))) void*)(&smem[_b][1][loff]), 16, 0, 0);    \
        __builtin_amdgcn_global_load_lds(                                                \
            (const __attribute__((address_space(1))) void*)(gB + _k + goff + (size_t)128 * K_DIM), \
            (__attribute__((address_space(3))) void*)(&smem[_b][1][loff + 4096]), 16, 0, 0); \
    } while (0)

    // prologue: stage tiles 0,1,2 (12 loads in flight)
    STAGE(0);
    STAGE(1);
    STAGE(2);

    for (int t = 0; t < NT; ++t) {
        // B1: close previous iteration's LDS reads before overwriting buf[(t+3)&3]
        __builtin_amdgcn_s_barrier();

        if (t < NT - 3) {
            STAGE(t + 3);
            asm volatile("s_waitcnt vmcnt(12)" ::: "memory");   // tiles t+1..t+3 may remain in flight
        } else if (t == NT - 3) {
            asm volatile("s_waitcnt vmcnt(8)" ::: "memory");
        } else if (t == NT - 2) {
            asm volatile("s_waitcnt vmcnt(4)" ::: "memory");
        } else {
            asm volatile("s_waitcnt vmcnt(0)" ::: "memory");
        }

        // B2: all waves observe tile t landed
        __builtin_amdgcn_s_barrier();

        const f16* Asb = &smem[t & 3][0][0];
        const f16* Bsb = &smem[t & 3][1][0];

        f16x8 af[8], bf[4];
        #pragma unroll
        for (int m = 0; m < 8; ++m)
            af[m] = *(const f16x8*)(Asb + aoffs[m]);
        #pragma unroll
        for (int n = 0; n < 4; ++n)
            bf[n] = *(const f16x8*)(Bsb + boffs[n]);

        __builtin_amdgcn_s_setprio(1);
        #pragma unroll
        for (int m = 0; m < 8; ++m)
            #pragma unroll
            for (int n = 0; n < 4; ++n)
                acc[m][n] = __builtin_amdgcn_mfma_f32_16x16x32_f16(af[m], bf[n], acc[m][n], 0, 0, 0);
        __builtin_amdgcn_s_setprio(0);
    }
#undef STAGE

    // epilogue: C/D layout col=lane&15, row=(lane>>4)*4+r (verified R1)
    #pragma unroll
    for (int m = 0; m < 8; ++m) {
        int grow = bm * BM + wr * 128 + m * 16 + fq * 4;
        #pragma unroll
        for (int n = 0; n < 4; ++n) {
            int gcol = bn * BN + wc * 64 + n * 16 + fr;
            float bv = bias[gcol];
            #pragma unroll
            for (int r = 0; r < 4; ++r)
                out[(size_t)(grow + r) * O_DIM + gcol] = acc[m][n][r] + bv;
        }
    }
}

// ---------------- fallback: correctness-first ----------------
__global__ __launch_bounds__(256) void fallback_kernel(const float* __restrict__ x,
                                                       const int* __restrict__ qidx,
                                                       const float* __restrict__ scales,
                                                       const float* __restrict__ babs,
                                                       const float* __restrict__ bias,
                                                       float* __restrict__ out) {
    __shared__ float xs[K_DIM];
    int n = blockIdx.x;
    int o = blockIdx.y * 256 + threadIdx.x;
    for (int i = threadIdx.x; i < K_DIM; i += 256)
        xs[i] = x[(size_t)n * K_DIM + i];
    __syncthreads();
    const int* qr = qidx + (size_t)o * K_DIM;
    float sum = 0.f;
    for (int b = 0; b < BPR; ++b) {
        float s2 = scales[o * BPR + b] * (1.0f / 127.0f);
        float b2 = fmaf(-128.0f, s2, babs[o * BPR + b]);
        for (int k = 0; k < QBLK; ++k)
            sum = fmaf(xs[b * QBLK + k], fmaf((float)qr[b * QBLK + k], s2, b2), sum);
    }
    out[(size_t)n * O_DIM + o] = sum + bias[o];
}

extern "C" void kernel_launch(void* const* d_in, const int* in_sizes, int n_in,
                              void* d_out, int out_size, void* d_ws, size_t ws_size,
                              hipStream_t stream) {
    const float* x      = (const float*)d_in[0];
    const int*   qidx   = (const int*)d_in[1];
    const float* scales = (const float*)d_in[2];
    const float* babs   = (const float*)d_in[3];
    const float* bias   = (const float*)d_in[4];
    float* out = (float*)d_out;

    const int nrows = in_sizes[0] / K_DIM;   // 4096

    const size_t xh_bytes = (size_t)nrows * K_DIM * sizeof(f16);
    const size_t wh_bytes = (size_t)O_DIM * K_DIM * sizeof(f16);

    if (ws_size >= xh_bytes + wh_bytes && (nrows % BM) == 0) {
        f16* xh = (f16*)d_ws;
        f16* wh = (f16*)((char*)d_ws + xh_bytes);

        int cvt_blocks = (int)(((size_t)nrows * K_DIM) / 2048);
        cvt_x_kernel<<<cvt_blocks, 256, 0, stream>>>(x, xh);

        int dq_blocks = (int)(((size_t)O_DIM * K_DIM) / 2048);
        dequant_w_kernel<<<dq_blocks, 256, 0, stream>>>(qidx, scales, babs, wh);

        int nwg = (nrows / BM) * NBN;    // 16*43 = 688, % 8 == 0
        gemm256_f16_kernel<<<nwg, 512, 0, stream>>>(xh, wh, bias, out);
    } else {
        dim3 grid(nrows, O_DIM / 256);
        fallback_kernel<<<grid, 256, 0, stream>>>(x, qidx, scales, babs, bias, out);
    }
}

// Round 3
// 702.892 us; speedup vs baseline: 1.0929x; 1.0346x over previous
//
#include <hip/hip_runtime.h>

#define K_DIM 4096
#define O_DIM 11008
#define QBLK  256
#define BPR   (K_DIM / QBLK)   // 16

typedef _Float16 f16;
typedef _Float16 f16x8 __attribute__((ext_vector_type(8)));
typedef float    f32x4 __attribute__((ext_vector_type(4)));

// ---------------- kernel 1: x fp32 -> f16 ----------------
__global__ __launch_bounds__(256) void cvt_x_kernel(const float* __restrict__ x,
                                                    f16* __restrict__ xh) {
    size_t i = ((size_t)blockIdx.x * 256 + threadIdx.x) * 8;
    float4 a = *(const float4*)(x + i);
    float4 b = *(const float4*)(x + i + 4);
    f16x8 h;
    h[0] = (f16)a.x; h[1] = (f16)a.y; h[2] = (f16)a.z; h[3] = (f16)a.w;
    h[4] = (f16)b.x; h[5] = (f16)b.y; h[6] = (f16)b.z; h[7] = (f16)b.w;
    *(f16x8*)(xh + i) = h;
}

// ---------------- kernel 2: dequant W -> f16 ----------------
__global__ __launch_bounds__(256) void dequant_w_kernel(const int* __restrict__ qidx,
                                                        const float* __restrict__ scales,
                                                        const float* __restrict__ babs,
                                                        f16* __restrict__ wh) {
    size_t e = ((size_t)blockIdx.x * 256 + threadIdx.x) * 8;
    int4 q0 = *(const int4*)(qidx + e);
    int4 q1 = *(const int4*)(qidx + e + 4);
    int sb = (int)(e >> 8);
    float s2 = scales[sb] * (1.0f / 127.0f);
    float b2 = fmaf(-128.0f, s2, babs[sb]);
    f16x8 h;
    h[0] = (f16)fmaf((float)q0.x, s2, b2);
    h[1] = (f16)fmaf((float)q0.y, s2, b2);
    h[2] = (f16)fmaf((float)q0.z, s2, b2);
    h[3] = (f16)fmaf((float)q0.w, s2, b2);
    h[4] = (f16)fmaf((float)q1.x, s2, b2);
    h[5] = (f16)fmaf((float)q1.y, s2, b2);
    h[6] = (f16)fmaf((float)q1.z, s2, b2);
    h[7] = (f16)fmaf((float)q1.w, s2, b2);
    *(f16x8*)(wh + e) = h;
}

// ---------------- kernel 3: 256x256, BK=64, 8-phase (4 phases/K-tile), counted vmcnt ----------------
// A: [4096, K] f16 row-major.  B: [O, K] f16 row-major.
// LDS: 2 dbuf x 4 halves (Aklo,Akhi,Bklo,Bkhi), each half = 256 rows x 32 f16 contiguous (16 KB).
#define BM 256
#define BN 256
#define BK 64
#define NT (K_DIM / BK)        // 64 K-tiles
#define NBN (O_DIM / BN)       // 43

__global__ __launch_bounds__(512, 2) void gemm8p_f16_kernel(const f16* __restrict__ A,
                                                            const f16* __restrict__ B,
                                                            const float* __restrict__ bias,
                                                            float* __restrict__ out) {
    __shared__ f16 sm[2][4][8192];   // 128 KiB: [dbuf][Aklo,Akhi,Bklo,Bkhi][256*32]

    // bijective XCD swizzle (688 blocks, % 8 == 0)
    int bid = blockIdx.x;
    int chunk = gridDim.x >> 3;
    int swz = (bid & 7) * chunk + (bid >> 3);
    int bm = swz / NBN;
    int bn = swz - bm * NBN;

    const int tid  = threadIdx.x;
    const int lane = tid & 63;
    const int wid  = tid >> 6;          // 8 waves
    const int wr   = wid >> 2;          // 0..1 -> row-half of 256 (128 rows each)
    const int wc   = wid & 3;           // 0..3 -> col block of 64
    const int fr   = lane & 15;
    const int fq   = lane >> 4;

    const f16* gA = A + (size_t)bm * BM * K_DIM;
    const f16* gB = B + (size_t)bn * BN * K_DIM;

    // staging: linear LDS dest, pre-swizzled global source (R2-proven involution)
    const int srow  = tid >> 2;                          // row within 128-row chunk
    const int sslot = (tid & 3) ^ ((tid >> 3) & 3);      // logical 16B slot
    const size_t gsoff = (size_t)srow * K_DIM + sslot * 8;
    const int ldst = tid * 8;                            // f16 offset in half-chunk

    // fragment read offsets within a half (row stride 32 f16 = 64 B, zero-conflict swizzle)
    int offa[2][4], offb[4];
    #pragma unroll
    for (int mh = 0; mh < 2; ++mh)
        #pragma unroll
        for (int ml = 0; ml < 4; ++ml) {
            int r = wr * 128 + mh * 64 + ml * 16 + fr;
            offa[mh][ml] = r * 32 + ((fq ^ ((r >> 1) & 3)) << 3);
        }
    #pragma unroll
    for (int n = 0; n < 4; ++n) {
        int r = wc * 64 + n * 16 + fr;
        offb[n] = r * 32 + ((fq ^ ((r >> 1) & 3)) << 3);
    }

    f32x4 acc[8][4];
    #pragma unroll
    for (int m = 0; m < 8; ++m)
        #pragma unroll
        for (int n = 0; n < 4; ++n)
            acc[m][n] = (f32x4){0.f, 0.f, 0.f, 0.f};

    // halves: 0=Aklo 1=Akhi 2=Bklo 3=Bkhi ; kh = h&1 ; op = h<2 ? A : B
#define STAGE_HALF(T_, h_)                                                                   \
    do {                                                                                     \
        const f16* gsrc_ = ((h_) < 2) ? gA : gB;                                             \
        size_t koff_ = (size_t)(T_) * BK + ((h_) & 1) * 32;                                  \
        __builtin_amdgcn_global_load_lds(                                                    \
            (const __attribute__((address_space(1))) void*)(gsrc_ + gsoff + koff_),          \
            (__attribute__((address_space(3))) void*)(&sm[(T_) & 1][h_][ldst]), 16, 0, 0);   \
        __builtin_amdgcn_global_load_lds(                                                    \
            (const __attribute__((address_space(1))) void*)(gsrc_ + gsoff + koff_ + (size_t)128 * K_DIM), \
            (__attribute__((address_space(3))) void*)(&sm[(T_) & 1][h_][ldst + 4096]), 16, 0, 0); \
    } while (0)

#define LOAD_AF(d_, kk_, mh_)                                                    \
    do {                                                                         \
        const f16* hb_ = &sm[d_][kk_][0];                                        \
        af[0] = *(const f16x8*)(hb_ + offa[mh_][0]);                             \
        af[1] = *(const f16x8*)(hb_ + offa[mh_][1]);                             \
        af[2] = *(const f16x8*)(hb_ + offa[mh_][2]);                             \
        af[3] = *(const f16x8*)(hb_ + offa[mh_][3]);                             \
    } while (0)

#define LOAD_BF(d_, kk_)                                                         \
    do {                                                                         \
        const f16* hb_ = &sm[d_][2 + (kk_)][0];                                  \
        bf[0] = *(const f16x8*)(hb_ + offb[0]);                                  \
        bf[1] = *(const f16x8*)(hb_ + offb[1]);                                  \
        bf[2] = *(const f16x8*)(hb_ + offb[2]);                                  \
        bf[3] = *(const f16x8*)(hb_ + offb[3]);                                  \
    } while (0)

#define MFMA16(mh_)                                                              \
    do {                                                                         \
        __builtin_amdgcn_s_setprio(1);                                           \
        _Pragma("unroll")                                                        \
        for (int ml = 0; ml < 4; ++ml)                                           \
            _Pragma("unroll")                                                    \
            for (int n = 0; n < 4; ++n)                                          \
                acc[(mh_) * 4 + ml][n] =                                         \
                    __builtin_amdgcn_mfma_f32_16x16x32_f16(af[ml], bf[n],        \
                                                           acc[(mh_) * 4 + ml][n], 0, 0, 0); \
        __builtin_amdgcn_s_setprio(0);                                           \
    } while (0)

    // prologue: steady-state issue order for tiles 0 and 1 (7 halves, 14 loads)
    STAGE_HALF(0, 2); STAGE_HALF(0, 0); STAGE_HALF(0, 3); STAGE_HALF(0, 1);
    STAGE_HALF(1, 2); STAGE_HALF(1, 0); STAGE_HALF(1, 3);
    asm volatile("s_waitcnt vmcnt(10)" ::: "memory");   // Bklo(0), Aklo(0) landed
    __builtin_amdgcn_s_barrier();

    for (int T = 0; T < NT; ++T) {
        const int d = T & 1;
        f16x8 af[4], bf[4];

        // ---- g1: (mh=0, kk=0) ----
        LOAD_AF(d, 0, 0);
        LOAD_BF(d, 0);
        if (T + 1 < NT) STAGE_HALF(T + 1, 1);           // Akhi(T+1) -> buf d^1 (dead since T-1.g4)
        __builtin_amdgcn_s_barrier();
        MFMA16(0);
        __builtin_amdgcn_s_barrier();

        // ---- g2: (mh=1, kk=0) ----
        LOAD_AF(d, 0, 1);                                // bf reused
        if (T + 2 < NT) STAGE_HALF(T + 2, 2);            // Bklo(T+2) -> buf d (Bklo dead after g1)
        if (T < NT - 2) asm volatile("s_waitcnt vmcnt(10)" ::: "memory");
        else            asm volatile("s_waitcnt vmcnt(0)" ::: "memory");
        __builtin_amdgcn_s_barrier();
        MFMA16(1);
        __builtin_amdgcn_s_barrier();

        // ---- g3: (mh=0, kk=1) ----
        LOAD_AF(d, 1, 0);
        LOAD_BF(d, 1);
        if (T + 2 < NT) STAGE_HALF(T + 2, 0);            // Aklo(T+2) (dead after g2)
        __builtin_amdgcn_s_barrier();
        MFMA16(0);
        __builtin_amdgcn_s_barrier();

        // ---- g4: (mh=1, kk=1) ----
        LOAD_AF(d, 1, 1);
        if (T + 2 < NT) STAGE_HALF(T + 2, 3);            // Bkhi(T+2) (dead after g3)
        if (T < NT - 2) asm volatile("s_waitcnt vmcnt(10)" ::: "memory");
        else            asm volatile("s_waitcnt vmcnt(0)" ::: "memory");
        __builtin_amdgcn_s_barrier();
        MFMA16(1);
        __builtin_amdgcn_s_barrier();
    }
#undef STAGE_HALF
#undef LOAD_AF
#undef LOAD_BF
#undef MFMA16

    // epilogue: C/D layout col=lane&15, row=(lane>>4)*4+r (R1/R2-verified)
    #pragma unroll
    for (int m = 0; m < 8; ++m) {
        int grow = bm * BM + wr * 128 + (m >> 2) * 64 + (m & 3) * 16 + fq * 4;
        #pragma unroll
        for (int n = 0; n < 4; ++n) {
            int gcol = bn * BN + wc * 64 + n * 16 + fr;
            float bv = bias[gcol];
            #pragma unroll
            for (int r = 0; r < 4; ++r)
                out[(size_t)(grow + r) * O_DIM + gcol] = acc[m][n][r] + bv;
        }
    }
}

// ---------------- fallback: correctness-first ----------------
__global__ __launch_bounds__(256) void fallback_kernel(const float* __restrict__ x,
                                                       const int* __restrict__ qidx,
                                                       const float* __restrict__ scales,
                                                       const float* __restrict__ babs,
                                                       const float* __restrict__ bias,
                                                       float* __restrict__ out) {
    __shared__ float xs[K_DIM];
    int n = blockIdx.x;
    int o = blockIdx.y * 256 + threadIdx.x;
    for (int i = threadIdx.x; i < K_DIM; i += 256)
        xs[i] = x[(size_t)n * K_DIM + i];
    __syncthreads();
    const int* qr = qidx + (size_t)o * K_DIM;
    float sum = 0.f;
    for (int b = 0; b < BPR; ++b) {
        float s2 = scales[o * BPR + b] * (1.0f / 127.0f);
        float b2 = fmaf(-128.0f, s2, babs[o * BPR + b]);
        for (int k = 0; k < QBLK; ++k)
            sum = fmaf(xs[b * QBLK + k], fmaf((float)qr[b * QBLK + k], s2, b2), sum);
    }
    out[(size_t)n * O_DIM + o] = sum + bias[o];
}

extern "C" void kernel_launch(void* const* d_in, const int* in_sizes, int n_in,
                              void* d_out, int out_size, void* d_ws, size_t ws_size,
                              hipStream_t stream) {
    const float* x      = (const float*)d_in[0];
    const int*   qidx   = (const int*)d_in[1];
    const float* scales = (const float*)d_in[2];
    const float* babs   = (const float*)d_in[3];
    const float* bias   = (const float*)d_in[4];
    float* out = (float*)d_out;

    const int nrows = in_sizes[0] / K_DIM;   // 4096

    const size_t xh_bytes = (size_t)nrows * K_DIM * sizeof(f16);
    const size_t wh_bytes = (size_t)O_DIM * K_DIM * sizeof(f16);

    if (ws_size >= xh_bytes + wh_bytes && (nrows % BM) == 0) {
        f16* xh = (f16*)d_ws;
        f16* wh = (f16*)((char*)d_ws + xh_bytes);

        int cvt_blocks = (int)(((size_t)nrows * K_DIM) / 2048);
        cvt_x_kernel<<<cvt_blocks, 256, 0, stream>>>(x, xh);

        int dq_blocks = (int)(((size_t)O_DIM * K_DIM) / 2048);
        dequant_w_kernel<<<dq_blocks, 256, 0, stream>>>(qidx, scales, babs, wh);

        int nwg = (nrows / BM) * NBN;    // 16*43 = 688, % 8 == 0
        gemm8p_f16_kernel<<<nwg, 512, 0, stream>>>(xh, wh, bias, out);
    } else {
        dim3 grid(nrows, O_DIM / 256);
        fallback_kernel<<<grid, 256, 0, stream>>>(x, qidx, scales, babs, bias, out);
    }
}